// Round 1
// baseline (113.211 us; speedup 1.0000x reference)
//
#include <hip/hip_runtime.h>

typedef unsigned short u16;
typedef __attribute__((ext_vector_type(8))) __bf16 bf16x8;
typedef __attribute__((ext_vector_type(4))) float f32x4;

static __device__ __forceinline__ u16 f2bf(float f) {
  unsigned u = __builtin_bit_cast(unsigned, f);
  u += 0x7fffu + ((u >> 16) & 1u);
  return (u16)(u >> 16);
}

static __device__ __forceinline__ f32x4 mfma16(bf16x8 a, bf16x8 b, f32x4 c) {
  return __builtin_amdgcn_mfma_f32_16x16x32_bf16(a, b, c, 0, 0, 0);
}

// ---------------- pack kernels ----------------
__global__ void pack_x_kernel(const float* __restrict__ x, u16* __restrict__ xb, int n) {
  int idx = blockIdx.x * 256 + threadIdx.x;
  if (idx < n) xb[idx] = f2bf(x[idx]);
}

// BTqkv[n][d], n = t*512 + h*64 + e  (t: 0=q,1=k,2=v), source W_t[h][d][e]
__global__ void pack_wqkv_kernel(const float* __restrict__ Wq, const float* __restrict__ Wk,
                                 const float* __restrict__ Wv, u16* __restrict__ BT) {
  int idx = blockIdx.x * 256 + threadIdx.x;
  if (idx >= 1536 * 512) return;
  int n = idx >> 9, d = idx & 511;
  int t = n >> 9, rem = n & 511;
  int h = rem >> 6, e = rem & 63;
  const float* W = (t == 0) ? Wq : ((t == 1) ? Wk : Wv);
  BT[idx] = f2bf(W[((size_t)h * 512 + d) * 64 + e]);
}

__global__ void pack_bias_kernel(const float* __restrict__ bq, const float* __restrict__ bk,
                                 const float* __restrict__ bv, float* __restrict__ bqkv) {
  int idx = blockIdx.x * 256 + threadIdx.x;
  if (idx >= 1536) return;
  int t = idx >> 9, rem = idx & 511;
  bqkv[idx] = (t == 0 ? bq : (t == 1 ? bk : bv))[rem];
}

// BTo[n][d] = Wo[d][n]
__global__ void pack_wo_kernel(const float* __restrict__ Wo, u16* __restrict__ BTo) {
  int idx = blockIdx.x * 256 + threadIdx.x;
  if (idx >= 512 * 512) return;
  int n = idx >> 9, d = idx & 511;
  BTo[idx] = f2bf(Wo[(size_t)d * 512 + n]);
}

// ---------------- GEMM: C[M][N] = A[M][K] @ BT[N][K]^T + bias ----------------
// 64x64 tile per 256-thread block, 4 waves in 2x2 grid, each wave 32x32 (2x2 MFMA frags)
template <int OUT_BF16>
__global__ __launch_bounds__(256) void gemm_bt_kernel(
    const u16* __restrict__ A, const u16* __restrict__ BT, const float* __restrict__ bias,
    u16* __restrict__ Cb, float* __restrict__ Cf, int M, int N, int K) {
  __shared__ __align__(16) u16 Alds[64][40];
  __shared__ __align__(16) u16 Blds[64][40];
  const int tid = threadIdx.x;
  const int w = tid >> 6, lane = tid & 63, g = lane >> 4, i = lane & 15;
  const int m0 = blockIdx.y * 64, n0 = blockIdx.x * 64;
  const int wr = (w >> 1) * 32, wc = (w & 1) * 32;
  f32x4 acc[2][2];
#pragma unroll
  for (int a = 0; a < 2; ++a)
#pragma unroll
    for (int b = 0; b < 2; ++b) acc[a][b] = f32x4{0.f, 0.f, 0.f, 0.f};

  const int srow = tid >> 2, sc = (tid & 3) * 8;
  const u16* Aptr = A + (size_t)(m0 + srow) * K + sc;
  const u16* Bptr = BT + (size_t)(n0 + srow) * K + sc;

  for (int k0 = 0; k0 < K; k0 += 32) {
    __syncthreads();
    *reinterpret_cast<uint4*>(&Alds[srow][sc]) = *reinterpret_cast<const uint4*>(Aptr + k0);
    *reinterpret_cast<uint4*>(&Blds[srow][sc]) = *reinterpret_cast<const uint4*>(Bptr + k0);
    __syncthreads();
    bf16x8 af[2], bfr[2];
#pragma unroll
    for (int mf = 0; mf < 2; ++mf)
      af[mf] = *reinterpret_cast<const bf16x8*>(&Alds[wr + mf * 16 + i][8 * g]);
#pragma unroll
    for (int nf = 0; nf < 2; ++nf)
      bfr[nf] = *reinterpret_cast<const bf16x8*>(&Blds[wc + nf * 16 + i][8 * g]);
#pragma unroll
    for (int mf = 0; mf < 2; ++mf)
#pragma unroll
      for (int nf = 0; nf < 2; ++nf) acc[mf][nf] = mfma16(af[mf], bfr[nf], acc[mf][nf]);
  }

#pragma unroll
  for (int mf = 0; mf < 2; ++mf) {
#pragma unroll
    for (int nf = 0; nf < 2; ++nf) {
#pragma unroll
      for (int r = 0; r < 4; ++r) {
        int row = m0 + wr + mf * 16 + 4 * g + r;
        int col = n0 + wc + nf * 16 + i;
        float v = acc[mf][nf][r] + bias[col];
        if (OUT_BF16)
          Cb[(size_t)row * N + col] = f2bf(v);
        else
          Cf[(size_t)row * N + col] = v;
      }
    }
  }
}

// ---------------- fused masked flash attention ----------------
// grid (S/64, H, B); 256 threads = 4 waves; wave w handles q rows [qt*64+w*16, +16)
__global__ __launch_bounds__(256) void attn_kernel(const u16* __restrict__ QKV,
                                                   u16* __restrict__ Cc) {
  __shared__ __align__(16) u16 Klds[32][72];   // K tile, rows j, cols e (padded)
  __shared__ __align__(16) u16 VTlds[64][40];  // V^T tile: [e][j] (padded)
  __shared__ __align__(16) u16 Plds[4][16][40];  // per-wave P: [qrow][j] (padded)
  const int tid = threadIdx.x;
  const int w = tid >> 6, lane = tid & 63, g = lane >> 4, i = lane & 15;
  const int qt = blockIdx.x, h = blockIdx.y, b = blockIdx.z;
  const int hm = (h < 4) ? h : 4;
  const int band = 1 << hm;
  const int modm = (band << 1) - 1;
  const int qbase = qt * 64 + w * 16;

  // Q fragments: A row = lane&15 -> q row qbase+i, k = e = 8g+b (+32)
  const size_t rowQ = (size_t)(b * 1024 + qbase + i) * 1536 + h * 64;
  const bf16x8 qf0 = *reinterpret_cast<const bf16x8*>(QKV + rowQ + 8 * g);
  const bf16x8 qf1 = *reinterpret_cast<const bf16x8*>(QKV + rowQ + 8 * g + 32);

  f32x4 acc[4];
#pragma unroll
  for (int et = 0; et < 4; ++et) acc[et] = f32x4{0.f, 0.f, 0.f, 0.f};
  float mrow[4], lrow[4];
#pragma unroll
  for (int r = 0; r < 4; ++r) { mrow[r] = -1e30f; lrow[r] = 0.f; }

  const int srow = tid >> 3;      // 0..31 (kv row in tile)
  const int sc = (tid & 7) * 8;   // 0..56 (e offset)
  const size_t kvbase = (size_t)(b * 1024) * 1536 + h * 64;

  for (int kv0 = 0; kv0 < 1024; kv0 += 32) {
    __syncthreads();
    {
      const u16* kp = QKV + kvbase + (size_t)(kv0 + srow) * 1536 + 512 + sc;
      *reinterpret_cast<uint4*>(&Klds[srow][sc]) = *reinterpret_cast<const uint4*>(kp);
      const u16* vp = QKV + kvbase + (size_t)(kv0 + srow) * 1536 + 1024 + sc;
      uint4 vv = *reinterpret_cast<const uint4*>(vp);
      const u16* pv = reinterpret_cast<const u16*>(&vv);
#pragma unroll
      for (int e = 0; e < 8; ++e) VTlds[sc + e][srow] = pv[e];  // transpose into [e][j]
    }
    __syncthreads();

    // QK^T for this 32-wide KV tile: 2 j-tiles x 2 e-halves
    f32x4 sfr[2];
#pragma unroll
    for (int jt = 0; jt < 2; ++jt) {
      bf16x8 kf0 = *reinterpret_cast<const bf16x8*>(&Klds[jt * 16 + i][8 * g]);
      bf16x8 kf1 = *reinterpret_cast<const bf16x8*>(&Klds[jt * 16 + i][8 * g + 32]);
      f32x4 s = f32x4{0.f, 0.f, 0.f, 0.f};
      s = mfma16(qf0, kf0, s);
      s = mfma16(qf1, kf1, s);
      const int kj = kv0 + jt * 16 + i;  // C col = lane&15
#pragma unroll
      for (int r = 0; r < 4; ++r) {      // C row = 4g+r
        int qi = qbase + 4 * g + r;
        int d = qi - kj;
        d = d < 0 ? -d : d;
        bool ok = (d <= band) || ((d & modm) == 0);
        s[r] = ok ? s[r] * 0.125f : -1e30f;
      }
      sfr[jt] = s;
    }

    // online softmax update (per q-row; rows live in (g, r), cols across 16 lanes)
    float corr[4];
#pragma unroll
    for (int r = 0; r < 4; ++r) {
      float t = fmaxf(sfr[0][r], sfr[1][r]);
      t = fmaxf(t, __shfl_xor(t, 1));
      t = fmaxf(t, __shfl_xor(t, 2));
      t = fmaxf(t, __shfl_xor(t, 4));
      t = fmaxf(t, __shfl_xor(t, 8));
      float mn = fmaxf(mrow[r], t);
      corr[r] = __expf(mrow[r] - mn);
      mrow[r] = mn;
    }
    float tsum[4] = {0.f, 0.f, 0.f, 0.f};
#pragma unroll
    for (int jt = 0; jt < 2; ++jt) {
#pragma unroll
      for (int r = 0; r < 4; ++r) {
        float p = __expf(sfr[jt][r] - mrow[r]);
        tsum[r] += p;
        Plds[w][4 * g + r][jt * 16 + i] = f2bf(p);
      }
    }
#pragma unroll
    for (int r = 0; r < 4; ++r) {
      float t = tsum[r];
      t += __shfl_xor(t, 1);
      t += __shfl_xor(t, 2);
      t += __shfl_xor(t, 4);
      t += __shfl_xor(t, 8);
      lrow[r] = lrow[r] * corr[r] + t;
    }
#pragma unroll
    for (int et = 0; et < 4; ++et)
#pragma unroll
      for (int r = 0; r < 4; ++r) acc[et][r] *= corr[r];

    // PV: A = P[16x32] (row i, k=8g+b), B = V[j][e] read from VT[e][j]
    bf16x8 pf = *reinterpret_cast<const bf16x8*>(&Plds[w][i][8 * g]);
#pragma unroll
    for (int et = 0; et < 4; ++et) {
      bf16x8 vf = *reinterpret_cast<const bf16x8*>(&VTlds[et * 16 + i][8 * g]);
      acc[et] = mfma16(pf, vf, acc[et]);
    }
  }

  // epilogue: normalize, write concat[b*1024+qi][h*64+e] bf16
#pragma unroll
  for (int et = 0; et < 4; ++et) {
#pragma unroll
    for (int r = 0; r < 4; ++r) {
      int qi = qbase + 4 * g + r;
      float o = acc[et][r] / lrow[r];
      Cc[(size_t)(b * 1024 + qi) * 512 + h * 64 + et * 16 + i] = f2bf(o);
    }
  }
}

// ---------------- launch ----------------
extern "C" void kernel_launch(void* const* d_in, const int* in_sizes, int n_in,
                              void* d_out, int out_size, void* d_ws, size_t ws_size,
                              hipStream_t stream) {
  const float* x = (const float*)d_in[0];
  const float* Wq = (const float*)d_in[1];
  const float* bq = (const float*)d_in[2];
  const float* Wk = (const float*)d_in[3];
  const float* bk = (const float*)d_in[4];
  const float* Wv = (const float*)d_in[5];
  const float* bv = (const float*)d_in[6];
  const float* Wo = (const float*)d_in[7];
  const float* bo = (const float*)d_in[8];
  float* out = (float*)d_out;

  char* ws = (char*)d_ws;
  u16* xb = (u16*)(ws);                    // 4 MB   [4096][512]
  u16* BTqkv = (u16*)(ws + (4u << 20));    // 1.5 MB [1536][512]
  u16* BTo = (u16*)(ws + (6u << 20));      // 0.5 MB [512][512]
  float* bqkv = (float*)(ws + (7u << 20)); // 6 KB
  u16* QKV = (u16*)(ws + (8u << 20));      // 12.6 MB [4096][1536]
  u16* Cc = (u16*)(ws + (21u << 20));      // 4 MB   [4096][512]

  const int NX = 4096 * 512;
  pack_x_kernel<<<(NX + 255) / 256, 256, 0, stream>>>(x, xb, NX);
  pack_wqkv_kernel<<<(1536 * 512 + 255) / 256, 256, 0, stream>>>(Wq, Wk, Wv, BTqkv);
  pack_bias_kernel<<<6, 256, 0, stream>>>(bq, bk, bv, bqkv);
  pack_wo_kernel<<<(512 * 512 + 255) / 256, 256, 0, stream>>>(Wo, BTo);

  // QKV projection: [4096,512] @ [512,1536] -> bf16 QKV
  gemm_bt_kernel<1><<<dim3(1536 / 64, 4096 / 64), 256, 0, stream>>>(
      xb, BTqkv, bqkv, QKV, nullptr, 4096, 1536, 512);

  // masked flash attention -> concat bf16 [4096][512]
  attn_kernel<<<dim3(16, 8, 4), 256, 0, stream>>>(QKV, Cc);

  // output projection: [4096,512] @ [512,512] -> f32 out
  gemm_bt_kernel<0><<<dim3(512 / 64, 4096 / 64), 256, 0, stream>>>(
      Cc, BTo, bo, nullptr, out, 4096, 512, 512);
}

// Round 3
// 81.956 us; speedup vs baseline: 1.3814x; 1.3814x over previous
//
#include <hip/hip_runtime.h>

typedef unsigned short u16;
typedef unsigned int u32;
typedef __attribute__((ext_vector_type(8))) __bf16 bf16x8;
typedef __attribute__((ext_vector_type(4))) float f32x4;
typedef __attribute__((ext_vector_type(16))) float f32x16;
typedef __attribute__((ext_vector_type(4))) u32 u32x4;

#if __has_builtin(__builtin_amdgcn_exp2f)
#define EXP2F(x) __builtin_amdgcn_exp2f(x)
#else
#define EXP2F(x) exp2f(x)
#endif

// 0.125 (1/sqrt(64)) * log2(e): folded into Wq/bq so scores are in exp2 domain
#define SC_Q 0.18033688011112042f

static __device__ __forceinline__ u16 f2bf(float f) {
  unsigned u = __builtin_bit_cast(unsigned, f);
  u += 0x7fffu + ((u >> 16) & 1u);
  return (u16)(u >> 16);
}

static __device__ __forceinline__ f32x4 mfma16(bf16x8 a, bf16x8 b, f32x4 c) {
  return __builtin_amdgcn_mfma_f32_16x16x32_bf16(a, b, c, 0, 0, 0);
}
static __device__ __forceinline__ f32x16 mfma32(bf16x8 a, bf16x8 b, f32x16 c) {
  return __builtin_amdgcn_mfma_f32_32x32x16_bf16(a, b, c, 0, 0, 0);
}

static __device__ __forceinline__ u32 cvtpk(float lo, float hi_) {
  u32 r;
  asm("v_cvt_pk_bf16_f32 %0, %1, %2" : "=v"(r) : "v"(lo), "v"(hi_));
  return r;
}

static __device__ __forceinline__ void barrier_raw() {
  asm volatile("" ::: "memory");
  __builtin_amdgcn_s_barrier();
  asm volatile("" ::: "memory");
}

static __device__ __forceinline__ void gload_lds16(const u16* g, u16* l) {
  __builtin_amdgcn_global_load_lds((const __attribute__((address_space(1))) u32*)g,
                                   (__attribute__((address_space(3))) u32*)l, 16, 0, 0);
}

// ---------------- pack kernels ----------------
__global__ void pack_x_kernel(const float* __restrict__ x, u16* __restrict__ xb, int n) {
  int idx = blockIdx.x * 256 + threadIdx.x;
  if (idx < n) xb[idx] = f2bf(x[idx]);
}

// BTqkv[n][d], n = t*512 + h*64 + e  (t: 0=q,1=k,2=v); Wq scaled by SC_Q
__global__ void pack_wqkv_kernel(const float* __restrict__ Wq, const float* __restrict__ Wk,
                                 const float* __restrict__ Wv, u16* __restrict__ BT) {
  int idx = blockIdx.x * 256 + threadIdx.x;
  if (idx >= 1536 * 512) return;
  int n = idx >> 9, d = idx & 511;
  int t = n >> 9, rem = n & 511;
  int h = rem >> 6, e = rem & 63;
  const float* W = (t == 0) ? Wq : ((t == 1) ? Wk : Wv);
  float sc = (t == 0) ? SC_Q : 1.0f;
  BT[idx] = f2bf(W[((size_t)h * 512 + d) * 64 + e] * sc);
}

__global__ void pack_bias_kernel(const float* __restrict__ bq, const float* __restrict__ bk,
                                 const float* __restrict__ bv, float* __restrict__ bqkv) {
  int idx = blockIdx.x * 256 + threadIdx.x;
  if (idx >= 1536) return;
  int t = idx >> 9, rem = idx & 511;
  float v = (t == 0 ? bq : (t == 1 ? bk : bv))[rem];
  bqkv[idx] = v * (t == 0 ? SC_Q : 1.0f);
}

// BTo[n][d] = Wo[d][n]
__global__ void pack_wo_kernel(const float* __restrict__ Wo, u16* __restrict__ BTo) {
  int idx = blockIdx.x * 256 + threadIdx.x;
  if (idx >= 512 * 512) return;
  int n = idx >> 9, d = idx & 511;
  BTo[idx] = f2bf(Wo[(size_t)d * 512 + n]);
}

// V [4096][1536 @1024+h*64] -> Vt [(b*8+h)*64+e][1024]
__global__ __launch_bounds__(256) void transpose_v_kernel(const u16* __restrict__ QKV,
                                                          u16* __restrict__ Vt) {
  __shared__ u16 t[64][72];
  const int tid = threadIdx.x;
  const int s0 = blockIdx.x * 64;
  const int bh = blockIdx.y;
  const int h = bh & 7, b = bh >> 3;
#pragma unroll
  for (int c2 = 0; c2 < 2; ++c2) {
    int slot = c2 * 256 + tid;
    int sr = slot >> 3, e8 = (slot & 7) * 8;
    uint4 vv = *reinterpret_cast<const uint4*>(
        QKV + (size_t)(b * 1024 + s0 + sr) * 1536 + 1024 + h * 64 + e8);
    *reinterpret_cast<uint4*>(&t[sr][e8]) = vv;
  }
  __syncthreads();
#pragma unroll
  for (int c2 = 0; c2 < 2; ++c2) {
    int slot = c2 * 256 + tid;
    int er = slot >> 3, j8 = (slot & 7) * 8;
    u16 tmp[8];
#pragma unroll
    for (int k = 0; k < 8; ++k) tmp[k] = t[j8 + k][er];
    *reinterpret_cast<uint4*>(Vt + (size_t)(bh * 64 + er) * 1024 + s0 + j8) =
        *reinterpret_cast<const uint4*>(tmp);
  }
}

// ---------------- GEMM: C[M][N] = A[M][K] @ BT[N][K]^T + bias ----------------
template <int OUT_BF16>
__global__ __launch_bounds__(256) void gemm_bt_kernel(
    const u16* __restrict__ A, const u16* __restrict__ BT, const float* __restrict__ bias,
    u16* __restrict__ Cb, float* __restrict__ Cf, int M, int N, int K) {
  __shared__ __align__(16) u16 Alds[64][40];
  __shared__ __align__(16) u16 Blds[64][40];
  const int tid = threadIdx.x;
  const int w = tid >> 6, lane = tid & 63, g = lane >> 4, i = lane & 15;
  const int m0 = blockIdx.y * 64, n0 = blockIdx.x * 64;
  const int wr = (w >> 1) * 32, wc = (w & 1) * 32;
  f32x4 acc[2][2];
#pragma unroll
  for (int a = 0; a < 2; ++a)
#pragma unroll
    for (int b = 0; b < 2; ++b) acc[a][b] = f32x4{0.f, 0.f, 0.f, 0.f};

  const int srow = tid >> 2, sc = (tid & 3) * 8;
  const u16* Aptr = A + (size_t)(m0 + srow) * K + sc;
  const u16* Bptr = BT + (size_t)(n0 + srow) * K + sc;

  for (int k0 = 0; k0 < K; k0 += 32) {
    __syncthreads();
    *reinterpret_cast<uint4*>(&Alds[srow][sc]) = *reinterpret_cast<const uint4*>(Aptr + k0);
    *reinterpret_cast<uint4*>(&Blds[srow][sc]) = *reinterpret_cast<const uint4*>(Bptr + k0);
    __syncthreads();
    bf16x8 af[2], bfr[2];
#pragma unroll
    for (int mf = 0; mf < 2; ++mf)
      af[mf] = *reinterpret_cast<const bf16x8*>(&Alds[wr + mf * 16 + i][8 * g]);
#pragma unroll
    for (int nf = 0; nf < 2; ++nf)
      bfr[nf] = *reinterpret_cast<const bf16x8*>(&Blds[wc + nf * 16 + i][8 * g]);
#pragma unroll
    for (int mf = 0; mf < 2; ++mf)
#pragma unroll
      for (int nf = 0; nf < 2; ++nf) acc[mf][nf] = mfma16(af[mf], bfr[nf], acc[mf][nf]);
  }

#pragma unroll
  for (int mf = 0; mf < 2; ++mf) {
#pragma unroll
    for (int nf = 0; nf < 2; ++nf) {
#pragma unroll
      for (int r = 0; r < 4; ++r) {
        int row = m0 + wr + mf * 16 + 4 * g + r;
        int col = n0 + wc + nf * 16 + i;
        float v = acc[mf][nf][r] + bias[col];
        if (OUT_BF16)
          Cb[(size_t)row * N + col] = f2bf(v);
        else
          Cf[(size_t)row * N + col] = v;
      }
    }
  }
}

// ---------------- attention v2: 32x32 swapped-QK, in-register P ----------------
// grid (8 qtiles of 128, 8 h, 4 b); 256 thr = 4 waves, wave w owns q rows [q0w, q0w+32)
__global__ __launch_bounds__(256) void attn2_kernel(const u16* __restrict__ QKV,
                                                    const u16* __restrict__ Vt,
                                                    u16* __restrict__ Cc) {
  __shared__ __align__(16) u16 Kl[2][4096];  // [64 j][8 eb-blocks of 8] XOR-swizzled
  __shared__ __align__(16) u16 Vl[2][4096];  // [64 e][8 jb-blocks of 8] XOR-swizzled
  __shared__ float l_lds[4][32];

  const int tid = threadIdx.x;
  const int w = tid >> 6, lane = tid & 63;
  const int col = lane & 31, hi = lane >> 5;
  const int h = blockIdx.y, b = blockIdx.z;
  const int bh = b * 8 + h;
  const int q0w = blockIdx.x * 128 + w * 32;
  const int hm = (h < 4) ? h : 4;
  const int band = 1 << hm;
  const int modm = (2 << hm) - 1;
  const int qrow = q0w + col;

  // Q fragments (B-operand): lane holds Q[qrow][16*et + 8*hi + b]
  bf16x8 qf[4];
  const size_t qoff = (size_t)(b * 1024 + qrow) * 1536 + h * 64 + 8 * hi;
#pragma unroll
  for (int et = 0; et < 4; ++et)
    qf[et] = *reinterpret_cast<const bf16x8*>(QKV + qoff + 16 * et);

  // dilation bias per C-reg r (invariant across kv tiles: 64 % 2^(hm+1) == 0)
  float bias[16];
#pragma unroll
  for (int r = 0; r < 16; ++r) {
    int c = (r & 3) + 8 * (r >> 2) + 4 * hi;
    bias[r] = (((qrow - c) & modm) == 0) ? 0.f : -1e30f;
  }

  f32x16 accO0 = {}, accO1 = {};
  float m_run = -1e30f, l_run = 0.f;

  // staging: slot -> linear LDS (slot*16B); global source pre-swizzled (rule #21)
  const int slot0 = tid, slot1 = tid + 256;
  const int kj0 = slot0 >> 3, keb0 = (slot0 & 7) ^ (kj0 & 7);
  const int kj1 = slot1 >> 3, keb1 = (slot1 & 7) ^ (kj1 & 7);
  const u16* kg0 = QKV + (size_t)(b * 1024 + kj0) * 1536 + 512 + h * 64 + keb0 * 8;
  const u16* kg1 = QKV + (size_t)(b * 1024 + kj1) * 1536 + 512 + h * 64 + keb1 * 8;
  const u16* vg0 = Vt + (size_t)(bh * 64 + kj0) * 1024 + keb0 * 8;  // e=kj0, jb=keb0
  const u16* vg1 = Vt + (size_t)(bh * 64 + kj1) * 1024 + keb1 * 8;

#define STAGE(bi, kv0)                                                  \
  do {                                                                  \
    gload_lds16(kg0 + (size_t)(kv0) * 1536, &Kl[bi][slot0 * 8]);        \
    gload_lds16(kg1 + (size_t)(kv0) * 1536, &Kl[bi][slot1 * 8]);        \
    gload_lds16(vg0 + (kv0), &Vl[bi][slot0 * 8]);                       \
    gload_lds16(vg1 + (kv0), &Vl[bi][slot1 * 8]);                       \
  } while (0)

  STAGE(0, 0);
  int buf = 0;

  for (int t = 0; t < 16; ++t) {
    const int kv0 = t * 64;
    if (t < 15) {
      STAGE(buf ^ 1, kv0 + 64);
      asm volatile("s_waitcnt vmcnt(4)" ::: "memory");
    } else {
      asm volatile("s_waitcnt vmcnt(0)" ::: "memory");
    }
    barrier_raw();

    const u16* Kb = Kl[buf];
    const u16* Vb = Vl[buf];

    // QK^T swapped: s = mfma(K, Q); D[m=j][n=q], lane: n=col, m=crow(r,hi)
    f32x16 s0 = {}, s1 = {};
#pragma unroll
    for (int et = 0; et < 4; ++et) {
      const int sw = ((2 * et + hi) ^ (col & 7)) << 3;
      bf16x8 kf0 = *reinterpret_cast<const bf16x8*>(&Kb[col * 64 + sw]);
      bf16x8 kf1 = *reinterpret_cast<const bf16x8*>(&Kb[(col + 32) * 64 + sw]);
      s0 = mfma32(kf0, qf[et], s0);
      s1 = mfma32(kf1, qf[et], s1);
    }

    // mask (scores already in exp2 domain)
    float p[32];
    const int dq = qrow - kv0;
    const bool near = (q0w <= kv0 + 63 + band) && (kv0 <= q0w + 31 + band);
    if (near) {
#pragma unroll
      for (int r = 0; r < 16; ++r) {
        const int c = (r & 3) + 8 * (r >> 2) + 4 * hi;
        int d0 = dq - c, d1 = d0 - 32;
        d0 = d0 < 0 ? -d0 : d0;
        d1 = d1 < 0 ? -d1 : d1;
        p[r] = (d0 <= band) ? s0[r] : s0[r] + bias[r];
        p[r + 16] = (d1 <= band) ? s1[r] : s1[r] + bias[r];
      }
    } else {
#pragma unroll
      for (int r = 0; r < 16; ++r) {
        p[r] = s0[r] + bias[r];
        p[r + 16] = s1[r] + bias[r];
      }
    }

    // row max across lane pair (q = col lives in lanes l and l+32)
    float mu = p[0];
#pragma unroll
    for (int j = 1; j < 32; ++j) mu = fmaxf(mu, p[j]);
    mu = fmaxf(mu, __shfl_xor(mu, 32));

    // defer-max (T13): rescale only on real growth
    if (__any(mu > m_run + 8.f)) {
      float mn = fmaxf(m_run, mu);
      float corr = EXP2F(m_run - mn);
      m_run = mn;
      l_run *= corr;
#pragma unroll
      for (int j = 0; j < 16; ++j) {
        accO0[j] *= corr;
        accO1[j] *= corr;
      }
    }

    float sum = 0.f;
#pragma unroll
    for (int j = 0; j < 32; ++j) {
      p[j] = EXP2F(p[j] - m_run);
      sum += p[j];
    }
    sum += __shfl_xor(sum, 32);
    l_run += sum;

    // P -> A-frag in-register (cvt_pk + shfl_xor lane^32 exchange), then PV
#pragma unroll
    for (int kt = 0; kt < 4; ++kt) {
      const float* pp = (kt < 2) ? p : p + 16;  // mt = kt>>1 (compile-time)
      const int R = (kt & 1) * 8;
      u32 A0 = cvtpk(pp[R + 0], pp[R + 1]);
      u32 A1 = cvtpk(pp[R + 2], pp[R + 3]);
      u32 B0 = cvtpk(pp[R + 4], pp[R + 5]);
      u32 B1 = cvtpk(pp[R + 6], pp[R + 7]);
      u32 xA0 = __shfl_xor(A0, 32), xA1 = __shfl_xor(A1, 32);
      u32 xB0 = __shfl_xor(B0, 32), xB1 = __shfl_xor(B1, 32);
      // hi=0 lane supplies k=0..7 -> keys 16kt+0..7  = {own A-words, partner A-words}
      // hi=1 lane supplies k=8..15 -> keys 16kt+8..15 = {partner B-words, own B-words}
      u32 w0 = hi ? xB0 : A0;
      u32 w1 = hi ? xB1 : A1;
      u32 w2 = hi ? B0 : xA0;
      u32 w3 = hi ? B1 : xA1;
      u32x4 pu = {w0, w1, w2, w3};
      bf16x8 paf = __builtin_bit_cast(bf16x8, pu);
      const int jb = 2 * kt + hi;
      {
        const int erow = col;  // nt = 0
        bf16x8 vf = *reinterpret_cast<const bf16x8*>(&Vb[erow * 64 + ((jb ^ (erow & 7)) << 3)]);
        accO0 = mfma32(paf, vf, accO0);
      }
      {
        const int erow = 32 + col;  // nt = 1
        bf16x8 vf = *reinterpret_cast<const bf16x8*>(&Vb[erow * 64 + ((jb ^ (erow & 7)) << 3)]);
        accO1 = mfma32(paf, vf, accO1);
      }
    }

    barrier_raw();
    buf ^= 1;
  }
#undef STAGE

  // epilogue: broadcast l per q-row via LDS, normalize, store bf16 concat
  if (lane < 32) l_lds[w][col] = l_run;
#pragma unroll
  for (int r = 0; r < 16; ++r) {
    const int c = (r & 3) + 8 * (r >> 2) + 4 * hi;
    const float inv = 1.0f / l_lds[w][c];
    const size_t row = (size_t)(b * 1024 + q0w + c) * 512 + h * 64;
    Cc[row + col] = f2bf(accO0[r] * inv);
    Cc[row + 32 + col] = f2bf(accO1[r] * inv);
  }
}

// ---------------- launch ----------------
extern "C" void kernel_launch(void* const* d_in, const int* in_sizes, int n_in,
                              void* d_out, int out_size, void* d_ws, size_t ws_size,
                              hipStream_t stream) {
  const float* x = (const float*)d_in[0];
  const float* Wq = (const float*)d_in[1];
  const float* bq = (const float*)d_in[2];
  const float* Wk = (const float*)d_in[3];
  const float* bk = (const float*)d_in[4];
  const float* Wv = (const float*)d_in[5];
  const float* bv = (const float*)d_in[6];
  const float* Wo = (const float*)d_in[7];
  const float* bo = (const float*)d_in[8];
  float* out = (float*)d_out;

  char* ws = (char*)d_ws;
  u16* xb = (u16*)(ws);                     // 4 MB   [4096][512]
  u16* BTqkv = (u16*)(ws + (4u << 20));     // 1.5 MB [1536][512]
  u16* BTo = (u16*)(ws + (6u << 20));       // 0.5 MB [512][512]
  float* bqkv = (float*)(ws + (7u << 20));  // 6 KB
  u16* QKV = (u16*)(ws + (8u << 20));       // 12.6 MB [4096][1536]
  u16* Cc = (u16*)(ws + (21u << 20));       // 4 MB   [4096][512]
  u16* Vt = (u16*)(ws + (25u << 20));       // 4 MB   [32*64][1024]

  const int NX = 4096 * 512;
  pack_x_kernel<<<(NX + 255) / 256, 256, 0, stream>>>(x, xb, NX);
  pack_wqkv_kernel<<<(1536 * 512 + 255) / 256, 256, 0, stream>>>(Wq, Wk, Wv, BTqkv);
  pack_bias_kernel<<<6, 256, 0, stream>>>(bq, bk, bv, bqkv);
  pack_wo_kernel<<<(512 * 512 + 255) / 256, 256, 0, stream>>>(Wo, BTo);

  // QKV projection: [4096,512] @ [512,1536] -> bf16 QKV (Wq pre-scaled)
  gemm_bt_kernel<1><<<dim3(1536 / 64, 4096 / 64), 256, 0, stream>>>(
      xb, BTqkv, bqkv, QKV, nullptr, 4096, 1536, 512);

  // V -> Vt
  transpose_v_kernel<<<dim3(16, 32), 256, 0, stream>>>(QKV, Vt);

  // attention
  attn2_kernel<<<dim3(8, 8, 4), 256, 0, stream>>>(QKV, Vt, Cc);

  // output projection
  gemm_bt_kernel<0><<<dim3(512 / 64, 4096 / 64), 256, 0, stream>>>(
      Cc, BTo, bo, nullptr, out, 4096, 512, 512);
}